// Round 1
// baseline (741.031 us; speedup 1.0000x reference)
//
#include <hip/hip_runtime.h>

#define N_PATHS 8192
#define T_STEPS 256
#define D_IN    44
#define H_SZ    8
#define G4      32      // 4*H
#define NGROUPS 1024
#define TC      16      // timesteps per chunk
#define LOG2E   1.4426950408889634f

// ---------------- workspace layout (floats) ----------------
// [0, 1408)            Wt   : W_ih transposed [d][g]
// [1408, 1440)         bias : b_ih + b_hh
// [1440, 1440+8192)    perm : path ids sorted by last_idx (int)
// [9632, 9632+8192)    s    : per-path score dot(h_last, fc_W)

__device__ __forceinline__ float sigm_f(float x) {
    // 1 / (1 + e^-x); __expf -> v_exp_f32, rcp -> v_rcp_f32 (~1 ulp, fine vs 2% threshold)
    return __builtin_amdgcn_rcpf(1.0f + __expf(-x));
}
__device__ __forceinline__ float tanh_f(float x) {
    // tanh(x) = 1 - 2/(1 + e^{2x}); saturates correctly at +/-inf
    return 1.0f - 2.0f * __builtin_amdgcn_rcpf(1.0f + __expf(2.0f * x));
}

// ---------------- prep: transpose weights + counting sort by last_idx ----------------
__global__ void prep_kernel(const float* __restrict__ W_ih, const float* __restrict__ b_ih,
                            const float* __restrict__ b_hh, const int* __restrict__ last_idx,
                            float* __restrict__ Wt, float* __restrict__ bias,
                            int* __restrict__ perm) {
    __shared__ int hist[256];
    __shared__ int off[256];
    const int tid = threadIdx.x;  // 256 threads
    hist[tid] = 0;
    // transpose W_ih [32][44] -> Wt [44][32] (uniform-address friendly for main kernel)
    for (int idx = tid; idx < G4 * D_IN; idx += 256) {
        int g = idx / D_IN, d = idx - g * D_IN;
        Wt[d * G4 + g] = W_ih[idx];
    }
    if (tid < G4) bias[tid] = b_ih[tid] + b_hh[tid];
    __syncthreads();
    for (int k = 0; k < N_PATHS / 256; ++k)
        atomicAdd(&hist[last_idx[k * 256 + tid]], 1);
    __syncthreads();
    if (tid == 0) {  // serial exclusive scan over 256 bins: trivial cost
        int run = 0;
        for (int i = 0; i < 256; ++i) { off[i] = run; run += hist[i]; }
    }
    __syncthreads();
    for (int k = 0; k < N_PATHS / 256; ++k) {
        int p = k * 256 + tid;
        int b = last_idx[p];
        int pos = atomicAdd(&off[b], 1);
        perm[pos] = p;   // order within a length-bin is arbitrary; harmless
    }
}

// ---------------- main fused LSTM kernel ----------------
// 1 wave per block, 4 length-sorted paths per wave, no __syncthreads needed.
// Phase 1 (64 lanes = 4 paths x 16 t): xg GEMM, SGPR-streamed weights -> LDS.
// Phase 2 (32 lanes = 4 paths x 8 units): recurrence, h exchanged via LDS (in-order within wave).
__global__ __launch_bounds__(64, 2)
void lstm_kernel(const float* __restrict__ x, const float* __restrict__ Whh,
                 const float* __restrict__ Wt, const float* __restrict__ bias,
                 const float* __restrict__ fcW, const int* __restrict__ last_idx,
                 const int* __restrict__ perm, float* __restrict__ sout) {
    // xg2[tc][pl*40 + g]: pl stride 40 == 8 mod 32 -> phase-2 reads conflict-free,
    // phase-1 float4 writes 2-way max (free). 16*160*4B = 10.2 KB.
    __shared__ float xg2[TC][160];
    __shared__ __align__(16) float hbuf[4][12];  // 12-pad: float4-aligned rows

    const int lane = threadIdx.x;
    const int b = blockIdx.x;  // 0..2047, sorted segments; round-robin dispatch balances CUs

    // uniform (scalar) path metadata
    const int p0 = perm[4 * b + 0], p1 = perm[4 * b + 1];
    const int p2 = perm[4 * b + 2], p3 = perm[4 * b + 3];
    const int l0 = last_idx[p0], l1 = last_idx[p1];
    const int l2 = last_idx[p2], l3 = last_idx[p3];
    const int wmax = max(max(l0, l1), max(l2, l3));

    // phase-1 ids: lane = tc*4 + pl  (keeps LDS write octets conflict-light)
    const int pl1 = lane & 3, tc1 = lane >> 2;
    // phase-2 ids
    const int pl2 = lane >> 3, j = lane & 7;
    const bool act2 = lane < 32;

    const int pg1 = pl1 == 0 ? p0 : pl1 == 1 ? p1 : pl1 == 2 ? p2 : p3;
    const int pg2 = pl2 == 0 ? p0 : pl2 == 1 ? p1 : pl2 == 2 ? p2 : p3;
    const int lst2 = pl2 == 0 ? l0 : pl2 == 1 ? l1 : pl2 == 2 ? l2 : l3;

    // preload W_hh rows {j, 8+j, 16+j, 24+j} -> 32 VGPRs
    float whh[4][8];
#pragma unroll
    for (int m = 0; m < 4; ++m) {
        const float4* r = (const float4*)(Whh + (m * 8 + j) * H_SZ);
        float4 a = r[0], c = r[1];
        whh[m][0] = a.x; whh[m][1] = a.y; whh[m][2] = a.z; whh[m][3] = a.w;
        whh[m][4] = c.x; whh[m][5] = c.y; whh[m][6] = c.z; whh[m][7] = c.w;
    }
    const float fcWj = fcW[j];

    float hval = 0.f, cval = 0.f, hlast = 0.f;
    if (act2) hbuf[pl2][j] = 0.f;   // h0 = 0 (read before first write in phase 2)

    const float* xrow_base = x + (size_t)pg1 * (T_STEPS * D_IN);
    const int nch = (wmax >> 4) + 1;  // truncate at per-wave max length (sorted -> ~2x saving)

    for (int ch = 0; ch < nch; ++ch) {
        const int t0 = ch * TC;
        // ---------------- phase 1: xg = bias + x . Wt ----------------
        {
            float acc[32];
#pragma unroll
            for (int g = 0; g < 32; ++g) acc[g] = bias[g];   // uniform -> SGPR, hoisted
            const float4* xr = (const float4*)(xrow_base + (t0 + tc1) * D_IN);
#pragma unroll
            for (int q = 0; q < 11; ++q) {
                float4 v = xr[q];
#pragma unroll
                for (int r = 0; r < 4; ++r) {
                    const float xd = (r == 0) ? v.x : (r == 1) ? v.y : (r == 2) ? v.z : v.w;
                    const int d = 4 * q + r;
#pragma unroll
                    for (int g = 0; g < 32; ++g)
                        acc[g] = fmaf(Wt[d * 32 + g], xd, acc[g]);  // Wt uniform -> s_load stream
                }
            }
#pragma unroll
            for (int k = 0; k < 8; ++k) {
                float4 v = make_float4(acc[4 * k], acc[4 * k + 1], acc[4 * k + 2], acc[4 * k + 3]);
                *(float4*)&xg2[tc1][pl1 * 40 + 4 * k] = v;
            }
        }
        // ---------------- phase 2: 16 recurrence steps ----------------
        if (act2) {
#pragma unroll
            for (int tt = 0; tt < TC; ++tt) {
                const float4 h01 = *(const float4*)&hbuf[pl2][0];
                const float4 h23 = *(const float4*)&hbuf[pl2][4];
                float pre[4];
#pragma unroll
                for (int m = 0; m < 4; ++m) {
                    float p = xg2[tt][pl2 * 40 + j + 8 * m];
                    p = fmaf(whh[m][0], h01.x, p); p = fmaf(whh[m][1], h01.y, p);
                    p = fmaf(whh[m][2], h01.z, p); p = fmaf(whh[m][3], h01.w, p);
                    p = fmaf(whh[m][4], h23.x, p); p = fmaf(whh[m][5], h23.y, p);
                    p = fmaf(whh[m][6], h23.z, p); p = fmaf(whh[m][7], h23.w, p);
                    pre[m] = p;
                }
                const float ig = sigm_f(pre[0]);
                const float fg = sigm_f(pre[1]);
                const float gg = tanh_f(pre[2]);
                const float og = sigm_f(pre[3]);
                cval = fmaf(fg, cval, ig * gg);
                hval = og * tanh_f(cval);
                const int t = t0 + tt;
                hlast = (t == lst2) ? hval : hlast;
                hbuf[pl2][j] = hval;   // same-wave LDS: in-order, no barrier needed
            }
        }
    }

    if (act2) {
        float v = hlast * fcWj;            // per-path score = dot(h_last, fc_W)
        v += __shfl_xor(v, 1);
        v += __shfl_xor(v, 2);
        v += __shfl_xor(v, 4);
        if (j == 0) sout[pg2] = v;
    }
}

// ---------------- finalize: segment-sum + softmax over 1024 groups ----------------
__global__ void finalize_kernel(const float* __restrict__ s, const int* __restrict__ gid,
                                float* __restrict__ out) {
    __shared__ float seg[NGROUPS];
    __shared__ float red[16];
    const int tid = threadIdx.x;  // 1024
    seg[tid] = 0.f;
    __syncthreads();
#pragma unroll
    for (int k = 0; k < 8; ++k) {
        const int p = k * 1024 + tid;
        atomicAdd(&seg[gid[p]], s[p]);
    }
    __syncthreads();
    const float v = seg[tid];  // logit (fc_b cancels exactly in softmax)
    const int wid = tid >> 6, ln = tid & 63;
    // ---- max reduce ----
    float m = v;
#pragma unroll
    for (int o = 32; o >= 1; o >>= 1) m = fmaxf(m, __shfl_xor(m, o));
    if (ln == 0) red[wid] = m;
    __syncthreads();
    if (tid < 16) {
        float mm = red[tid];
#pragma unroll
        for (int o = 8; o >= 1; o >>= 1) mm = fmaxf(mm, __shfl_xor(mm, o));
        red[tid] = mm;
    }
    __syncthreads();
    const float vmax = red[0];
    __syncthreads();  // protect red[] reuse
    // ---- sum reduce ----
    const float e = __expf(v - vmax);
    float ss = e;
#pragma unroll
    for (int o = 32; o >= 1; o >>= 1) ss += __shfl_xor(ss, o);
    if (ln == 0) red[wid] = ss;
    __syncthreads();
    if (tid < 16) {
        float s2 = red[tid];
#pragma unroll
        for (int o = 8; o >= 1; o >>= 1) s2 += __shfl_xor(s2, o);
        red[tid] = s2;
    }
    __syncthreads();
    const float tot = red[0];
    out[tid] = e / tot;
}

extern "C" void kernel_launch(void* const* d_in, const int* in_sizes, int n_in,
                              void* d_out, int out_size, void* d_ws, size_t ws_size,
                              hipStream_t stream) {
    const float* x      = (const float*)d_in[0];
    const float* W_ih   = (const float*)d_in[1];
    const float* W_hh   = (const float*)d_in[2];
    const float* b_ih   = (const float*)d_in[3];
    const float* b_hh   = (const float*)d_in[4];
    const float* fcW    = (const float*)d_in[5];
    // d_in[6] = fc_b: constant shift of all logits -> cancels in softmax, skipped
    const int* last_idx = (const int*)d_in[7];
    const int* gid      = (const int*)d_in[8];

    float* wsf  = (float*)d_ws;
    float* Wt   = wsf;
    float* bias = wsf + 1408;
    int*   perm = (int*)(wsf + 1440);
    float* sarr = wsf + 1440 + 8192;
    float* out  = (float*)d_out;

    hipLaunchKernelGGL(prep_kernel, dim3(1), dim3(256), 0, stream,
                       W_ih, b_ih, b_hh, last_idx, Wt, bias, perm);
    hipLaunchKernelGGL(lstm_kernel, dim3(N_PATHS / 4), dim3(64), 0, stream,
                       x, W_hh, Wt, bias, fcW, last_idx, perm, sarr);
    hipLaunchKernelGGL(finalize_kernel, dim3(1), dim3(1024), 0, stream,
                       sarr, gid, out);
}